// Round 3
// baseline (2346.954 us; speedup 1.0000x reference)
//
#include <hip/hip_runtime.h>

// Sizes
#define T_STEPS 16
#define BATCH 16
// conv1: [B,1,100,768] -> [B,16,50,384], k5 s2 p2   (LIF, fp64 path)
// conv2: [B,16,50,384] -> [B,32,25,192], k3 s2 p1   (LIF, fp64 path)
// conv3: [B,32,25,192] -> [B,64,25,192], k3 s1 p1 + relu   (fp32)
// conv4: [B,64,25,192] -> [B,1,25,192],  k3 s1 p1          (fp32)
// resize bilinear x4 (align_corners=False) + softplus -> [B,1,100,768]

#define XHW (100*768)                // 76800 per (t,b)
#define M1_ELEMS (BATCH*16*50*384)   // 4,915,200
#define M2_ELEMS (BATCH*32*25*192)   // 2,457,600
#define H3_ELEMS (BATCH*64*25*192)   // 4,915,200
#define C4_ELEMS (BATCH*25*192)      // 76,800

// ---------------- K1: conv1 + LIF1 (fp64, 2 output cols per thread) ----------
__global__ __launch_bounds__(256) void k1_conv1_lif(
    const float* __restrict__ x,    // [B,100,768] (one timestep)
    const float* __restrict__ w1,   // [16,1,5,5]
    const float* __restrict__ b1,   // [16]
    double* __restrict__ mem1,      // [B,16,50,384] fp64 state
    float* __restrict__ s1)         // [B,16,50,384] spikes 0/1
{
    __shared__ double wsm[400];
    __shared__ double bsm[16];
    // BUG FIX (R2): block has 256 threads; the old `if (tid<400)` guard left
    // wsm[256..399] (out-channels 10..15) uninitialized -> deterministic 0.33 err.
    for (int i = threadIdx.x; i < 400; i += 256) wsm[i] = (double)w1[i];
    if (threadIdx.x < 16) bsm[threadIdx.x] = (double)b1[threadIdx.x];
    __syncthreads();

    int gid = blockIdx.x * 256 + threadIdx.x;    // (b, oh, j), j in [0,192)
    int j  = gid % 192;
    int t2 = gid / 192;
    int oh = t2 % 50;
    int b  = t2 / 50;
    int ow0 = 2 * j;

    const float* xb = x + b * XHW;
    double patch[5][7];
    int ih0 = oh * 2 - 2, iw0 = ow0 * 2 - 2;
#pragma unroll
    for (int kh = 0; kh < 5; kh++) {
        int ih = ih0 + kh;
        bool okh = (unsigned)ih < 100u;
#pragma unroll
        for (int c = 0; c < 7; c++) {
            int iw = iw0 + c;
            patch[kh][c] = (okh && (unsigned)iw < 768u) ? (double)xb[ih * 768 + iw] : 0.0;
        }
    }

    int base = ((b * 16) * 50 + oh) * 384 + ow0;
#pragma unroll
    for (int oc = 0; oc < 16; oc++) {
        double a0 = bsm[oc], a1 = a0;
#pragma unroll
        for (int kh = 0; kh < 5; kh++) {
#pragma unroll
            for (int kw = 0; kw < 5; kw++) {
                double w = wsm[oc * 25 + kh * 5 + kw];
                a0 = fma(patch[kh][kw],     w, a0);
                a1 = fma(patch[kh][kw + 2], w, a1);
            }
        }
        int idx = base + oc * (50 * 384);
        double m0 = mem1[idx] * 0.5 + a0;
        double m1 = mem1[idx + 1] * 0.5 + a1;
        bool f0 = (m0 >= 1.0), f1 = (m1 >= 1.0);
        s1[idx]     = f0 ? 1.0f : 0.0f;
        s1[idx + 1] = f1 ? 1.0f : 0.0f;
        mem1[idx]     = f0 ? 0.0 : m0;
        mem1[idx + 1] = f1 ? 0.0 : m1;
    }
}

// ---------------- K2: conv2 + LIF2 (fp64, 2 cols, oc in 2 groups of 16) ------
__global__ __launch_bounds__(128) void k2_conv2_lif(
    const float* __restrict__ s1,   // [B,16,50,384]
    const float* __restrict__ w2,   // [32,16,3,3]
    const float* __restrict__ b2,   // [32]
    double* __restrict__ mem2)      // [B,32,25,192] fp64 state
{
    __shared__ double wsm[16 * 9 * 32];   // [ic*9+kk][oc]
    __shared__ double bsm[32];
    for (int i = threadIdx.x; i < 4608; i += 128) {
        int oc = i & 31, r = i >> 5;      // r = ic*9 + kk
        wsm[i] = (double)w2[oc * 144 + r];
    }
    if (threadIdx.x < 32) bsm[threadIdx.x] = (double)b2[threadIdx.x];
    __syncthreads();

    int gid = blockIdx.x * 128 + threadIdx.x;    // (b, oh, j), j in [0,96)
    int j  = gid % 96;
    int t2 = gid / 96;
    int oh = t2 % 25;
    int b  = t2 / 25;
    int ow0 = 2 * j;

    int ih0 = oh * 2 - 1, iw0 = ow0 * 2 - 1;
    const float* sb = s1 + b * (16 * 50 * 384);
    int base = ((b * 32) * 25 + oh) * 192 + ow0;

    for (int g = 0; g < 2; g++) {                 // two groups of 16 out-chans
        double acc0[16], acc1[16];
#pragma unroll
        for (int o = 0; o < 16; o++) { acc0[o] = bsm[g * 16 + o]; acc1[o] = acc0[o]; }

        for (int ic = 0; ic < 16; ic++) {
            const float* sc = sb + ic * (50 * 384);
#pragma unroll
            for (int kh = 0; kh < 3; kh++) {
                int ih = ih0 + kh;
                bool okh = (unsigned)ih < 50u;
                double row[5];
#pragma unroll
                for (int c = 0; c < 5; c++) {
                    int iw = iw0 + c;
                    row[c] = (okh && (unsigned)iw < 384u) ? (double)sc[ih * 384 + iw] : 0.0;
                }
#pragma unroll
                for (int kw = 0; kw < 3; kw++) {
                    double v0 = row[kw], v1 = row[kw + 2];
                    const double* wp = &wsm[((ic * 3 + kh) * 3 + kw) * 32 + g * 16];
#pragma unroll
                    for (int o = 0; o < 16; o++) {
                        double w = wp[o];
                        acc0[o] = fma(v0, w, acc0[o]);
                        acc1[o] = fma(v1, w, acc1[o]);
                    }
                }
            }
        }

#pragma unroll
        for (int o = 0; o < 16; o++) {
            int idx = base + (g * 16 + o) * (25 * 192);
            double m0 = mem2[idx] * 0.5 + acc0[o];
            double m1 = mem2[idx + 1] * 0.5 + acc1[o];
            mem2[idx]     = (m0 >= 1.0) ? 0.0 : m0;
            mem2[idx + 1] = (m1 >= 1.0) ? 0.0 : m1;
        }
    }
}

// ---------------- K3: conv3 + relu (fp32, 2 cols x 32-oc half per thread) ----
__global__ __launch_bounds__(256) void k3_conv3_relu(
    const double* __restrict__ mem2, // [B,32,25,192] fp64 state
    const float* __restrict__ w3,    // [64,32,3,3]
    const float* __restrict__ b3,    // [64]
    float* __restrict__ h)           // [B,64,25,192]
{
    __shared__ float wsm[32 * 9 * 32];   // [ic*9+kk][oc_local]
    __shared__ float bsm[32];
    int ocbase = blockIdx.y * 32;
    for (int i = threadIdx.x; i < 9216; i += 256) {
        int oc = i & 31, r = i >> 5;     // r = ic*9 + kk  (ic < 32)
        wsm[i] = w3[(ocbase + oc) * 288 + r];
    }
    if (threadIdx.x < 32) bsm[threadIdx.x] = b3[ocbase + threadIdx.x];
    __syncthreads();

    int gid = blockIdx.x * 256 + threadIdx.x;    // (b, oh, j), j in [0,96)
    int j  = gid % 96;
    int t2 = gid / 96;
    int oh = t2 % 25;
    int b  = t2 / 25;
    int ow0 = 2 * j;

    float acc0[32], acc1[32];
#pragma unroll
    for (int oc = 0; oc < 32; oc++) { acc0[oc] = bsm[oc]; acc1[oc] = bsm[oc]; }

    const double* mb = mem2 + b * (32 * 25 * 192);
    for (int ic = 0; ic < 32; ic++) {
        const double* mc = mb + ic * (25 * 192);
#pragma unroll
        for (int kh = 0; kh < 3; kh++) {
            int ih = oh - 1 + kh;
            bool okh = (unsigned)ih < 25u;
            float row[4];
#pragma unroll
            for (int c = 0; c < 4; c++) {
                int iw = ow0 - 1 + c;
                row[c] = (okh && (unsigned)iw < 192u) ? (float)mc[ih * 192 + iw] : 0.f;
            }
#pragma unroll
            for (int kw = 0; kw < 3; kw++) {
                float v0 = row[kw], v1 = row[kw + 1];
                const float* wp = &wsm[((ic * 3 + kh) * 3 + kw) * 32];
#pragma unroll
                for (int oc = 0; oc < 32; oc++) {
                    float w = wp[oc];
                    acc0[oc] = fmaf(v0, w, acc0[oc]);
                    acc1[oc] = fmaf(v1, w, acc1[oc]);
                }
            }
        }
    }

    int base = ((b * 64 + ocbase) * 25 + oh) * 192 + ow0;
#pragma unroll
    for (int oc = 0; oc < 32; oc++) {
        int idx = base + oc * (25 * 192);
        h[idx]     = fmaxf(acc0[oc], 0.f);
        h[idx + 1] = fmaxf(acc1[oc], 0.f);
    }
}

// ---------------- K4: conv4 (fp32) ----------------
__global__ __launch_bounds__(256) void k4_conv4(
    const float* __restrict__ h,    // [B,64,25,192]
    const float* __restrict__ w4,   // [1,64,3,3]
    const float* __restrict__ b4,   // [1]
    float* __restrict__ c4)         // [B,25,192]
{
    __shared__ float wsm[576];
    for (int i = threadIdx.x; i < 576; i += 256) wsm[i] = w4[i];
    __syncthreads();

    int gid = blockIdx.x * 256 + threadIdx.x;    // (b, oh, ow)
    int ow = gid % 192;
    int t2 = gid / 192;
    int oh = t2 % 25;
    int b  = t2 / 25;

    float acc = b4[0];
    const float* hb = h + b * (64 * 25 * 192);
    for (int ic = 0; ic < 64; ic++) {
        const float* hc = hb + ic * (25 * 192);
#pragma unroll
        for (int kh = 0; kh < 3; kh++) {
            int ih = oh - 1 + kh;
            bool okh = (unsigned)ih < 25u;
#pragma unroll
            for (int kw = 0; kw < 3; kw++) {
                int iw = ow - 1 + kw;
                float v = (okh && (unsigned)iw < 192u) ? hc[ih * 192 + iw] : 0.f;
                acc = fmaf(v, wsm[ic * 9 + kh * 3 + kw], acc);
            }
        }
    }
    c4[gid] = acc;
}

// ---------------- K5: bilinear x4 (align_corners=False) + softplus ----------
__global__ __launch_bounds__(256) void k5_resize_softplus(
    const float* __restrict__ c4,   // [B,25,192]
    float* __restrict__ out)        // [B,100,768]
{
    int gid = blockIdx.x * 256 + threadIdx.x;
    int ox = gid % 768;
    int t2 = gid / 768;
    int oy = t2 % 100;
    int b  = t2 / 100;

    float sy = (oy + 0.5f) * 0.25f - 0.5f;
    float sx = (ox + 0.5f) * 0.25f - 0.5f;
    int y0 = (int)floorf(sy); float fy = sy - (float)y0;
    int x0 = (int)floorf(sx); float fx = sx - (float)x0;
    int y1 = y0 + 1, x1 = x0 + 1;
    y0 = y0 < 0 ? 0 : (y0 > 24 ? 24 : y0);
    y1 = y1 < 0 ? 0 : (y1 > 24 ? 24 : y1);
    x0 = x0 < 0 ? 0 : (x0 > 191 ? 191 : x0);
    x1 = x1 < 0 ? 0 : (x1 > 191 ? 191 : x1);

    const float* cb = c4 + b * 4800;
    float v00 = cb[y0 * 192 + x0], v01 = cb[y0 * 192 + x1];
    float v10 = cb[y1 * 192 + x0], v11 = cb[y1 * 192 + x1];
    float v = (1.f - fy) * ((1.f - fx) * v00 + fx * v01)
            +        fy  * ((1.f - fx) * v10 + fx * v11);
    // stable softplus: max(v,0) + log1p(exp(-|v|))
    float r = fmaxf(v, 0.f) + log1pf(expf(-fabsf(v)));
    out[gid] = r;
}

extern "C" void kernel_launch(void* const* d_in, const int* in_sizes, int n_in,
                              void* d_out, int out_size, void* d_ws, size_t ws_size,
                              hipStream_t stream) {
    const float* x_seq = (const float*)d_in[0];
    const float* w1 = (const float*)d_in[1];
    const float* b1 = (const float*)d_in[2];
    const float* w2 = (const float*)d_in[3];
    const float* b2 = (const float*)d_in[4];
    const float* w3 = (const float*)d_in[5];
    const float* b3 = (const float*)d_in[6];
    const float* w4 = (const float*)d_in[7];
    const float* b4 = (const float*)d_in[8];
    float* out = (float*)d_out;

    // ws layout (bytes):
    //   mem1d : double[M1_ELEMS]  = 39,321,600 B
    //   mem2d : double[M2_ELEMS]  = 19,660,800 B
    //   s1    : float [M1_ELEMS]  = 19,660,800 B  (reused as h in decoder)
    //   c4    : float [C4_ELEMS]  reuse of mem1d region (scan is done)
    char* wsb = (char*)d_ws;
    double* mem1 = (double*)wsb;
    double* mem2 = (double*)(wsb + (size_t)M1_ELEMS * 8);
    float*  s1   = (float*)(wsb + (size_t)M1_ELEMS * 8 + (size_t)M2_ELEMS * 8);
    float*  h    = s1;               // decoder reuse (s1 dead after scan)
    float*  c4o  = (float*)wsb;      // decoder reuse (mem1 dead after scan)

    // zero LIF state (ws is poisoned 0xAA before every call); 0.0 == all-zero bytes
    hipMemsetAsync(mem1, 0, (size_t)(M1_ELEMS + M2_ELEMS) * sizeof(double), stream);

    for (int t = 0; t < T_STEPS; t++) {
        const float* xt = x_seq + (size_t)t * BATCH * XHW;
        k1_conv1_lif<<<600, 256, 0, stream>>>(xt, w1, b1, mem1, s1);
        k2_conv2_lif<<<300, 128, 0, stream>>>(s1, w2, b2, mem2);
    }
    k3_conv3_relu<<<dim3(150, 2), 256, 0, stream>>>(mem2, w3, b3, h);
    k4_conv4<<<300, 256, 0, stream>>>(h, w4, b4, c4o);
    k5_resize_softplus<<<4800, 256, 0, stream>>>(c4o, out);
}

// Round 4
// 1328.503 us; speedup vs baseline: 1.7666x; 1.7666x over previous
//
#include <hip/hip_runtime.h>

// Sizes
#define T_STEPS 16
#define BATCH 16
// conv1: [B,1,100,768] -> [B,16,50,384], k5 s2 p2   (LIF, fp32)
// conv2: [B,16,50,384] -> [B,32,25,192], k3 s2 p1   (LIF, fp32, spikes as u8)
// conv3: [B,32,25,192] -> [B,64,25,192], k3 s1 p1 + relu
// conv4: [B,64,25,192] -> [B,1,25,192],  k3 s1 p1 (ic-split + atomicAdd)
// resize bilinear x4 (align_corners=False) + softplus -> [B,1,100,768]

#define XHW (100*768)                // 76800 per (t,b)
#define M1_ELEMS (BATCH*16*50*384)   // 4,915,200
#define M2_ELEMS (BATCH*32*25*192)   // 2,457,600
#define H3_ELEMS (BATCH*64*25*192)   // 4,915,200
#define C4_ELEMS (BATCH*25*192)      // 76,800

// ---------- K1: conv1 + LIF1 (fp32, 2 cols x 8 oc per thread, 1200 blocks) ----
__global__ __launch_bounds__(256) void k1_conv1_lif(
    const float* __restrict__ x,    // [B,100,768] (one timestep)
    const float* __restrict__ w1,   // [16,1,5,5]
    const float* __restrict__ b1,   // [16]
    float* __restrict__ mem1,       // [B,16,50,384]
    unsigned char* __restrict__ s1) // [B,16,50,384] spikes 0/1
{
    __shared__ float wsm[200];      // 8 oc x 25
    __shared__ float bsm[8];
    int ocbase = blockIdx.y * 8;
    for (int i = threadIdx.x; i < 200; i += 256) wsm[i] = w1[ocbase * 25 + i];
    if (threadIdx.x < 8) bsm[threadIdx.x] = b1[ocbase + threadIdx.x];
    __syncthreads();

    int gid = blockIdx.x * 256 + threadIdx.x;    // (b, oh, j), j in [0,192)
    int j  = gid % 192;
    int t2 = gid / 192;
    int oh = t2 % 50;
    int b  = t2 / 50;
    int ow0 = 2 * j;

    const float* xb = x + b * XHW;
    float patch[5][7];
    int ih0 = oh * 2 - 2, iw0 = ow0 * 2 - 2;
#pragma unroll
    for (int kh = 0; kh < 5; kh++) {
        int ih = ih0 + kh;
        bool okh = (unsigned)ih < 100u;
#pragma unroll
        for (int c = 0; c < 7; c++) {
            int iw = iw0 + c;
            patch[kh][c] = (okh && (unsigned)iw < 768u) ? xb[ih * 768 + iw] : 0.f;
        }
    }

#pragma unroll
    for (int oc = 0; oc < 8; oc++) {
        float a0 = bsm[oc], a1 = a0;
#pragma unroll
        for (int kh = 0; kh < 5; kh++) {
#pragma unroll
            for (int kw = 0; kw < 5; kw++) {
                float w = wsm[oc * 25 + kh * 5 + kw];
                a0 = fmaf(patch[kh][kw],     w, a0);
                a1 = fmaf(patch[kh][kw + 2], w, a1);
            }
        }
        int idx = ((b * 16 + ocbase + oc) * 50 + oh) * 384 + ow0;
        float2 m = *(const float2*)&mem1[idx];
        float m0 = m.x * 0.5f + a0;
        float m1 = m.y * 0.5f + a1;
        bool f0 = (m0 >= 1.0f), f1 = (m1 >= 1.0f);
        float2 mo; mo.x = f0 ? 0.f : m0; mo.y = f1 ? 0.f : m1;
        *(float2*)&mem1[idx] = mo;
        unsigned short sv = (unsigned short)((f0 ? 1u : 0u) | ((f1 ? 1u : 0u) << 8));
        *(unsigned short*)&s1[idx] = sv;
    }
}

// ---------- K2: conv2 + LIF2 (fp32, 2 cols x 8 oc per thread, 600 blocks) -----
__global__ __launch_bounds__(256) void k2_conv2_lif(
    const unsigned char* __restrict__ s1, // [B,16,50,384] spikes
    const float* __restrict__ w2,   // [32,16,3,3]
    const float* __restrict__ b2,   // [32]
    float* __restrict__ mem2)       // [B,32,25,192]
{
    __shared__ float wsm[16 * 9 * 8];    // [r = ic*9+kk][oc_local 8]
    __shared__ float bsm[8];
    int ocbase = blockIdx.y * 8;
    for (int i = threadIdx.x; i < 1152; i += 256) {
        int o = i & 7, r = i >> 3;
        wsm[i] = w2[(ocbase + o) * 144 + r];
    }
    if (threadIdx.x < 8) bsm[threadIdx.x] = b2[ocbase + threadIdx.x];
    __syncthreads();

    int gid = blockIdx.x * 256 + threadIdx.x;    // (b, oh, j), j in [0,96)
    int j  = gid % 96;
    int t2 = gid / 96;
    int oh = t2 % 25;
    int b  = t2 / 25;
    int ow0 = 2 * j;

    float acc0[8], acc1[8];
#pragma unroll
    for (int o = 0; o < 8; o++) { acc0[o] = bsm[o]; acc1[o] = bsm[o]; }

    int ih0 = oh * 2 - 1, iw0 = ow0 * 2 - 1;
    const unsigned char* sb = s1 + b * (16 * 50 * 384);
    for (int ic = 0; ic < 16; ic++) {
        const unsigned char* sc = sb + ic * (50 * 384);
#pragma unroll
        for (int kh = 0; kh < 3; kh++) {
            int ih = ih0 + kh;
            bool okh = (unsigned)ih < 50u;
            float row[5];
#pragma unroll
            for (int c = 0; c < 5; c++) {
                int iw = iw0 + c;
                row[c] = (okh && (unsigned)iw < 384u) ? (float)sc[ih * 384 + iw] : 0.f;
            }
#pragma unroll
            for (int kw = 0; kw < 3; kw++) {
                float v0 = row[kw], v1 = row[kw + 2];
                const float* wp = &wsm[((ic * 3 + kh) * 3 + kw) * 8];
#pragma unroll
                for (int o = 0; o < 8; o++) {
                    float w = wp[o];
                    acc0[o] = fmaf(v0, w, acc0[o]);
                    acc1[o] = fmaf(v1, w, acc1[o]);
                }
            }
        }
    }

#pragma unroll
    for (int o = 0; o < 8; o++) {
        int idx = ((b * 32 + ocbase + o) * 25 + oh) * 192 + ow0;
        float2 m = *(const float2*)&mem2[idx];
        float m0 = m.x * 0.5f + acc0[o];
        float m1 = m.y * 0.5f + acc1[o];
        float2 mo;
        mo.x = (m0 >= 1.0f) ? 0.f : m0;
        mo.y = (m1 >= 1.0f) ? 0.f : m1;
        *(float2*)&mem2[idx] = mo;
    }
}

// ---------- K3: conv3 + relu (1 col x 16 oc per thread, 1600 blocks x 192t) ---
__global__ __launch_bounds__(192) void k3_conv3_relu(
    const float* __restrict__ mem2,  // [B,32,25,192]
    const float* __restrict__ w3,    // [64,32,3,3]
    const float* __restrict__ b3,    // [64]
    float* __restrict__ h)           // [B,64,25,192]
{
    __shared__ float wsm[32 * 9 * 16];   // [r = ic*9+kk][oc_local 16]
    __shared__ float bsm[16];
    int ocbase = blockIdx.y * 16;
    for (int i = threadIdx.x; i < 4608; i += 192) {
        int o = i & 15, r = i >> 4;
        wsm[i] = w3[(ocbase + o) * 288 + r];
    }
    if (threadIdx.x < 16) bsm[threadIdx.x] = b3[ocbase + threadIdx.x];
    __syncthreads();

    int j  = threadIdx.x;            // col 0..191
    int oh = blockIdx.x % 25;
    int b  = blockIdx.x / 25;

    float acc[16];
#pragma unroll
    for (int o = 0; o < 16; o++) acc[o] = bsm[o];

    const float* mb = mem2 + b * (32 * 25 * 192);
    for (int ic = 0; ic < 32; ic++) {
        const float* mc = mb + ic * (25 * 192);
#pragma unroll
        for (int kh = 0; kh < 3; kh++) {
            int ih = oh - 1 + kh;
            bool okh = (unsigned)ih < 25u;
            float row[3];
#pragma unroll
            for (int c = 0; c < 3; c++) {
                int iw = j - 1 + c;
                row[c] = (okh && (unsigned)iw < 192u) ? mc[ih * 192 + iw] : 0.f;
            }
#pragma unroll
            for (int kw = 0; kw < 3; kw++) {
                float v = row[kw];
                const float* wp = &wsm[((ic * 3 + kh) * 3 + kw) * 16];
#pragma unroll
                for (int o = 0; o < 16; o++)
                    acc[o] = fmaf(v, wp[o], acc[o]);
            }
        }
    }

#pragma unroll
    for (int o = 0; o < 16; o++) {
        int idx = ((b * 64 + ocbase + o) * 25 + oh) * 192 + j;
        h[idx] = fmaxf(acc[o], 0.f);
    }
}

// ---------- K4: conv4 partials (16-ic slice per blockIdx.y, atomicAdd) --------
__global__ __launch_bounds__(256) void k4_conv4(
    const float* __restrict__ h,    // [B,64,25,192]
    const float* __restrict__ w4,   // [1,64,3,3]
    float* __restrict__ c4)         // [B,25,192] (pre-zeroed; bias added in k5)
{
    __shared__ float wsm[144];      // 16 ic x 9
    int icbase = blockIdx.y * 16;
    for (int i = threadIdx.x; i < 144; i += 256) wsm[i] = w4[icbase * 9 + i];
    __syncthreads();

    int gid = blockIdx.x * 256 + threadIdx.x;    // (b, oh, ow)
    int ow = gid % 192;
    int t2 = gid / 192;
    int oh = t2 % 25;
    int b  = t2 / 25;

    float acc = 0.f;
    const float* hb = h + (b * 64 + icbase) * (25 * 192);
    for (int ic = 0; ic < 16; ic++) {
        const float* hc = hb + ic * (25 * 192);
#pragma unroll
        for (int kh = 0; kh < 3; kh++) {
            int ih = oh - 1 + kh;
            bool okh = (unsigned)ih < 25u;
#pragma unroll
            for (int kw = 0; kw < 3; kw++) {
                int iw = ow - 1 + kw;
                float v = (okh && (unsigned)iw < 192u) ? hc[ih * 192 + iw] : 0.f;
                acc = fmaf(v, wsm[ic * 9 + kh * 3 + kw], acc);
            }
        }
    }
    atomicAdd(&c4[gid], acc);
}

// ---------- K5: + bias, bilinear x4 (align_corners=False), softplus ----------
__global__ __launch_bounds__(256) void k5_resize_softplus(
    const float* __restrict__ c4,   // [B,25,192]
    const float* __restrict__ b4,   // [1]
    float* __restrict__ out)        // [B,100,768]
{
    int gid = blockIdx.x * 256 + threadIdx.x;
    int ox = gid % 768;
    int t2 = gid / 768;
    int oy = t2 % 100;
    int b  = t2 / 100;

    float bias = b4[0];
    float sy = (oy + 0.5f) * 0.25f - 0.5f;
    float sx = (ox + 0.5f) * 0.25f - 0.5f;
    int y0 = (int)floorf(sy); float fy = sy - (float)y0;
    int x0 = (int)floorf(sx); float fx = sx - (float)x0;
    int y1 = y0 + 1, x1 = x0 + 1;
    y0 = y0 < 0 ? 0 : (y0 > 24 ? 24 : y0);
    y1 = y1 < 0 ? 0 : (y1 > 24 ? 24 : y1);
    x0 = x0 < 0 ? 0 : (x0 > 191 ? 191 : x0);
    x1 = x1 < 0 ? 0 : (x1 > 191 ? 191 : x1);

    const float* cb = c4 + b * 4800;
    float v00 = cb[y0 * 192 + x0] + bias, v01 = cb[y0 * 192 + x1] + bias;
    float v10 = cb[y1 * 192 + x0] + bias, v11 = cb[y1 * 192 + x1] + bias;
    float v = (1.f - fy) * ((1.f - fx) * v00 + fx * v01)
            +        fy  * ((1.f - fx) * v10 + fx * v11);
    // stable softplus: max(v,0) + log1p(exp(-|v|))
    out[gid] = fmaxf(v, 0.f) + log1pf(expf(-fabsf(v)));
}

extern "C" void kernel_launch(void* const* d_in, const int* in_sizes, int n_in,
                              void* d_out, int out_size, void* d_ws, size_t ws_size,
                              hipStream_t stream) {
    const float* x_seq = (const float*)d_in[0];
    const float* w1 = (const float*)d_in[1];
    const float* b1 = (const float*)d_in[2];
    const float* w2 = (const float*)d_in[3];
    const float* b2 = (const float*)d_in[4];
    const float* w3 = (const float*)d_in[5];
    const float* b3 = (const float*)d_in[6];
    const float* w4 = (const float*)d_in[7];
    const float* b4 = (const float*)d_in[8];
    float* out = (float*)d_out;

    // ws layout: [mem1 f32 M1][mem2 f32 M2][c4 f32 C4][s1 u8 M1][h f32 H3]
    float* ws = (float*)d_ws;
    float* mem1 = ws;
    float* mem2 = ws + M1_ELEMS;
    float* c4o  = ws + M1_ELEMS + M2_ELEMS;
    unsigned char* s1 = (unsigned char*)(ws + M1_ELEMS + M2_ELEMS + C4_ELEMS);
    float* h = (float*)(s1 + M1_ELEMS);   // M1 bytes, 16B-aligned

    // zero mem1, mem2, c4 in one memset (contiguous)
    hipMemsetAsync(mem1, 0, (size_t)(M1_ELEMS + M2_ELEMS + C4_ELEMS) * sizeof(float), stream);

    for (int t = 0; t < T_STEPS; t++) {
        const float* xt = x_seq + (size_t)t * BATCH * XHW;
        k1_conv1_lif<<<dim3(600, 2), 256, 0, stream>>>(xt, w1, b1, mem1, s1);
        k2_conv2_lif<<<dim3(150, 4), 256, 0, stream>>>(s1, w2, b2, mem2);
    }
    k3_conv3_relu<<<dim3(400, 4), 192, 0, stream>>>(mem2, w3, b3, h);
    k4_conv4<<<dim3(300, 4), 256, 0, stream>>>(h, w4, c4o);
    k5_resize_softplus<<<4800, 256, 0, stream>>>(c4o, b4, out);
}